// Round 6
// baseline (264.671 us; speedup 1.0000x reference)
//
#include <hip/hip_runtime.h>
#include <hip/hip_bf16.h>

#define ENS 7
#define SDIM 30
#define ADIM 8
#define DIN 38          // SDIM + ADIM
#define HID 200
#define DOUT 31         // SDIM + RDIM
#define NHL 3           // hidden layers
#define HS 232          // hA row stride in elems (116 words -> 2-way max on b128 reads)
#define MT 64           // rows per block

typedef __bf16 bf16x8 __attribute__((ext_vector_type(8)));
typedef float f32x4 __attribute__((ext_vector_type(4)));

// ws layout (ushort elems): bf16 weights pre-swizzled into MFMA fragment order.
// Fragment (ct,st) = contiguous 512-ushort (1024 B) block at (ct*S + st)*512;
// element (lane, j) = W[k = st*32 + (lane>>4)*8 + j][n = ct*16 + (lane&15)]  (0 if OOB)
// Consumed as the MFMA A operand (m = out-col). Ownership (NT=13): wave w owns
// cts {3w,3w+1,3w+2} fully + row-slice rt=w of ct 12  -> perfect 13/13/13/13 balance.
#define U_L1 13312
#define U_H 46592
#define OFF_HD2 (U_L1 + NHL * U_H)            // 153088
#define PER_E (OFF_HD2 + 14336)               // 167424
#define WS_TOTAL (ENS * PER_E)                // 1171968 ushorts = 2.34 MB

__device__ __forceinline__ unsigned short f2bf(float f) {
    unsigned u = __float_as_uint(f);
    u += 0x7fffu + ((u >> 16) & 1u);          // RNE
    return (unsigned short)(u >> 16);
}

__device__ __forceinline__ unsigned pk2(float a, float b) {
    __hip_bfloat162 h = __float22bfloat162_rn(make_float2(a, b));
    return *reinterpret_cast<unsigned*>(&h);
}

__device__ __forceinline__ float softplusf(float x) {
    return fmaxf(x, 0.f) + __logf(1.f + __expf(-fabsf(x)));
}

// ---- prep: fp32 weights -> bf16 fragment-order in ws (layout unchanged since R4) ----
__global__ void prep_kernel(const float* __restrict__ W1, const float* __restrict__ Wh,
                            const float* __restrict__ Wmu, const float* __restrict__ Wsig,
                            unsigned short* __restrict__ ws) {
    int idx = blockIdx.x * 256 + threadIdx.x;
    if (idx >= WS_TOTAL) return;
    int e = idx / PER_E, r = idx % PER_E;
    int j = r & 7, lane = (r >> 3) & 63;
    int l16 = lane & 15, q = lane >> 4;
    float v = 0.f;
    if (r < U_L1) {                            // layer 1 (S=2)
        int fi = r >> 9;
        int ct = fi >> 1, st = fi & 1;
        int k = st * 32 + q * 8 + j, n = ct * 16 + l16;
        if (k < DIN && n < HID) v = W1[(e * DIN + k) * HID + n];
    } else if (r < OFF_HD2) {                  // hidden layers (S=7)
        int rh = r - U_L1;
        int l = rh / U_H, r2 = rh % U_H;
        int fi = r2 >> 9;
        int ct = fi / 7, st = fi % 7;
        int k = st * 32 + q * 8 + j, n = ct * 16 + l16;
        if (k < HID && n < HID) v = Wh[((l * ENS + e) * HID + (long)k) * HID + n];
    } else {                                   // heads (mu cols 0..30, sig cols 32..62)
        int r2 = r - OFF_HD2;
        int fi = r2 >> 9;
        int ct = fi / 7, st = fi % 7;
        int k = st * 32 + q * 8 + j, n = ct * 16 + l16;
        if (k < HID) {
            if (n < DOUT) v = Wmu[(e * HID + k) * DOUT + n];
            else if (n >= 32 && n < 32 + DOUT) v = Wsig[(e * HID + k) * DOUT + (n - 32)];
        }
    }
    ws[idx] = f2bf(v);
}

// One layer, balanced ownership. Weights = A operand, activations (LDS) = B operand.
// D[m = out-col][n = batch-row]: lane holds 4 consecutive out-cols of row (l16-based).
// At the last K-step, prefetches the NEXT layer's st=0 fragments into bq (these have
// no hA dependency, so they issue before the epilogue barrier and hide L2 latency).
template<int S, int OWN, bool SH, int NS, int NOWN, bool NSH>
__device__ __forceinline__ void runLayer(const unsigned short* __restrict__ fo,
                                         const unsigned short* __restrict__ fs,
                                         const unsigned short* __restrict__ nfo,
                                         const unsigned short* __restrict__ nfs,
                                         const unsigned short* hA,
                                         int swv, int l16, int quad,
                                         f32x4 (&accO)[4][3], f32x4& accS,
                                         bf16x8 (&bq)[4]) {
#pragma unroll
    for (int r = 0; r < 4; r++)
#pragma unroll
        for (int c = 0; c < 3; c++) accO[r][c] = (f32x4){0.f, 0.f, 0.f, 0.f};
    accS = (f32x4){0.f, 0.f, 0.f, 0.f};

#pragma unroll
    for (int st = 0; st < S; ++st) {
        bf16x8 bn[4];
        if (st + 1 < S) {
#pragma unroll
            for (int c = 0; c < OWN; c++) bn[c] = *((const bf16x8*)(fo + (c * S + st + 1) * 512));
            if (SH) bn[3] = *((const bf16x8*)(fs + (st + 1) * 512));
        } else if (NS > 0) {
#pragma unroll
            for (int c = 0; c < NOWN; c++) bn[c] = *((const bf16x8*)(nfo + (c * NS) * 512));
            if (NSH) bn[3] = *((const bf16x8*)(nfs));
        }
        bf16x8 af[4];
#pragma unroll
        for (int r = 0; r < 4; r++)
            af[r] = *((const bf16x8*)(hA + (r * 16 + l16) * HS + st * 32 + quad * 8));
        bf16x8 afs;
        if (SH) afs = *((const bf16x8*)(hA + (swv * 16 + l16) * HS + st * 32 + quad * 8));
#pragma unroll
        for (int c = 0; c < OWN; c++)
#pragma unroll
            for (int r = 0; r < 4; r++)
                accO[r][c] = __builtin_amdgcn_mfma_f32_16x16x32_bf16(bq[c], af[r], accO[r][c], 0, 0, 0);
        if (SH) accS = __builtin_amdgcn_mfma_f32_16x16x32_bf16(bq[3], afs, accS, 0, 0, 0);
        if (st + 1 < S || NS > 0) {
#pragma unroll
            for (int c = 0; c < 4; c++) bq[c] = bn[c];
        }
    }
}

// ---- fused 5-layer ensemble MLP ----
__launch_bounds__(256, 4)
__global__ void ens_mlp_kernel(const float* __restrict__ s, const float* __restrict__ a,
                               const float* __restrict__ b1, const float* __restrict__ bh,
                               const float* __restrict__ bmu, const float* __restrict__ bsig,
                               const float* __restrict__ maxs, const float* __restrict__ mins,
                               const float* __restrict__ maxr, const float* __restrict__ minr,
                               const unsigned short* __restrict__ ws,
                               float* __restrict__ out, int N) {
    __shared__ unsigned short hA[MT * HS];     // 29696 B, activations (bf16) -- only LDS

    const int tid = threadIdx.x;
    const int wv = tid >> 6, lane = tid & 63;
    const int quad = lane >> 4, l16 = lane & 15;
    const int swv = __builtin_amdgcn_readfirstlane(wv);   // wave-uniform -> SGPR addressing
    const int bid = blockIdx.x;
    const int e = bid % ENS, n0 = (bid / ENS) * MT;

    // zero hA (K-pad cols must be 0)
    for (int i = tid; i < MT * HS / 8; i += 256) ((uint4*)hA)[i] = make_uint4(0, 0, 0, 0);
    __syncthreads();

    // stage x = concat(s, a) -> hA cols 0..37 (bf16)
    {
        int m = tid & 63, cg = tid >> 6;
        long g = n0 + m;
        const float* srow = s + (g * ENS + e) * SDIM;
        const float* arow = a + (g * ENS + e) * ADIM;
#pragma unroll
        for (int k = 0; k < 10; k++) {
            int c = cg * 10 + k;
            if (c < DIN) {
                float v = (c < SDIM) ? srow[c] : arow[c - SDIM];
                hA[m * HS + c] = f2bf(v);
            }
        }
    }
    __syncthreads();

    // scalar fragment base pointers (+ lane*16 B per-lane part)
    const unsigned short* we = ws + e * PER_E;
    const unsigned short* L1o = we + swv * 3 * 2 * 512 + lane * 8;
    const unsigned short* L1s = we + 12 * 2 * 512 + lane * 8;
    const unsigned short* H0o = we + U_L1 + swv * 3 * 7 * 512 + lane * 8;
    const unsigned short* H0s = we + U_L1 + 12 * 7 * 512 + lane * 8;
    const unsigned short* H1o = H0o + U_H;
    const unsigned short* H1s = H0s + U_H;
    const unsigned short* H2o = H1o + U_H;
    const unsigned short* H2s = H1s + U_H;
    const unsigned short* HDo = we + OFF_HD2 + swv * 7 * 512 + lane * 8;

    f32x4 accO[4][3];   // own col-tiles: [row-tile][c]
    f32x4 accS;         // shared ct12, row-tile = swv
    bf16x8 bq[4];

    // bias + swish -> hA. Own cts: col < 192 always (unconditional float4 bias).
    // Shared ct12: cols 192..207; pad cols (>=200) have zero weights+bias -> writes 0,
    // which is exactly the K-pad zero the next layer needs.
    auto epiH = [&](const float* bias) {
#pragma unroll
        for (int c = 0; c < 3; c++) {
            int col = (3 * swv + c) * 16 + quad * 4;
            float4 bc4 = *((const float4*)(bias + col));
#pragma unroll
            for (int r = 0; r < 4; r++) {
                float v0 = accO[r][c][0] + bc4.x, v1 = accO[r][c][1] + bc4.y;
                float v2 = accO[r][c][2] + bc4.z, v3 = accO[r][c][3] + bc4.w;
                v0 *= __builtin_amdgcn_rcpf(1.f + __expf(-v0));
                v1 *= __builtin_amdgcn_rcpf(1.f + __expf(-v1));
                v2 *= __builtin_amdgcn_rcpf(1.f + __expf(-v2));
                v3 *= __builtin_amdgcn_rcpf(1.f + __expf(-v3));
                *((uint2*)(hA + (r * 16 + l16) * HS + col)) = make_uint2(pk2(v0, v1), pk2(v2, v3));
            }
        }
        {
            int col = 192 + quad * 4;
            float4 bc4 = make_float4(0.f, 0.f, 0.f, 0.f);
            if (col < HID) bc4 = *((const float4*)(bias + col));   // quad 0,1 only
            float v0 = accS[0] + bc4.x, v1 = accS[1] + bc4.y;
            float v2 = accS[2] + bc4.z, v3 = accS[3] + bc4.w;
            v0 *= __builtin_amdgcn_rcpf(1.f + __expf(-v0));
            v1 *= __builtin_amdgcn_rcpf(1.f + __expf(-v1));
            v2 *= __builtin_amdgcn_rcpf(1.f + __expf(-v2));
            v3 *= __builtin_amdgcn_rcpf(1.f + __expf(-v3));
            *((uint2*)(hA + (swv * 16 + l16) * HS + col)) = make_uint2(pk2(v0, v1), pk2(v2, v3));
        }
    };

    // initial fragment load (L1, st=0)
#pragma unroll
    for (int c = 0; c < 3; c++) bq[c] = *((const bf16x8*)(L1o + (c * 2) * 512));
    bq[3] = *((const bf16x8*)(L1s));

    runLayer<2, 3, true, 7, 3, true>(L1o, L1s, H0o, H0s, hA, swv, l16, quad, accO, accS, bq);
    __syncthreads();
    epiH(b1 + e * HID);
    __syncthreads();
    runLayer<7, 3, true, 7, 3, true>(H0o, H0s, H1o, H1s, hA, swv, l16, quad, accO, accS, bq);
    __syncthreads();
    epiH(bh + (0 * ENS + e) * HID);
    __syncthreads();
    runLayer<7, 3, true, 7, 3, true>(H1o, H1s, H2o, H2s, hA, swv, l16, quad, accO, accS, bq);
    __syncthreads();
    epiH(bh + (1 * ENS + e) * HID);
    __syncthreads();
    runLayer<7, 3, true, 7, 1, false>(H2o, H2s, HDo, (const unsigned short*)nullptr,
                                      hA, swv, l16, quad, accO, accS, bq);
    __syncthreads();
    epiH(bh + (2 * ENS + e) * HID);
    __syncthreads();
    runLayer<7, 1, false, 0, 0, false>(HDo, (const unsigned short*)nullptr,
                                       (const unsigned short*)nullptr, (const unsigned short*)nullptr,
                                       hA, swv, l16, quad, accO, accS, bq);
    // no barrier: head tail reads only registers, writes only global

    // head tail: wave owns ct = swv -> lane holds cols swv*16+quad*4+{0..3}
    // (mu block 0..31 for swv<2, sigma block 32..63 for swv>=2), rows r*16+l16.
    const long off1 = (long)N * ENS * SDIM;    // ds_sg
    const long off2 = 2 * off1;                // r_mu
    const long off3 = off2 + (long)N * ENS;    // r_sg
    {
        const bool isSig = (swv >= 2);
        const int c0 = (swv & 1) * 16 + quad * 4;
        float bias_i[4], mx_i[4], mn_i[4];
#pragma unroll
        for (int i = 0; i < 4; i++) {
            int c = c0 + i;
            bias_i[i] = (c < DOUT) ? (isSig ? bsig : bmu)[e * DOUT + c] : 0.f;
            if (isSig) {
                mx_i[i] = (c < SDIM) ? maxs[c] : maxr[0];
                mn_i[i] = (c < SDIM) ? mins[c] : minr[0];
            }
        }
#pragma unroll
        for (int r = 0; r < 4; r++) {
            long g = n0 + r * 16 + l16;
            long rowbase = (g * ENS + e) * SDIM;
#pragma unroll
            for (int i = 0; i < 4; i++) {
                int c = c0 + i;
                if (c < DOUT) {
                    float v = accO[r][0][i] + bias_i[i];
                    if (!isSig) {
                        if (c < SDIM) out[rowbase + c] = v;
                        else out[off2 + g * ENS + e] = v;
                    } else {
                        v = 0.5f * (mx_i[i] - softplusf(mx_i[i] - 2.f * v));
                        v = 0.5f * (mn_i[i] + softplusf(2.f * v - mn_i[i]));
                        v = __expf(v);
                        if (c < SDIM) out[off1 + rowbase + c] = v;
                        else out[off3 + g * ENS + e] = v;
                    }
                }
            }
        }
    }
}

extern "C" void kernel_launch(void* const* d_in, const int* in_sizes, int n_in,
                              void* d_out, int out_size, void* d_ws, size_t ws_size,
                              hipStream_t stream) {
    const float* s    = (const float*)d_in[0];
    const float* a    = (const float*)d_in[1];
    const float* W1   = (const float*)d_in[2];
    const float* b1   = (const float*)d_in[3];
    const float* Wh   = (const float*)d_in[4];
    const float* bh   = (const float*)d_in[5];
    const float* Wmu  = (const float*)d_in[6];
    const float* bmu  = (const float*)d_in[7];
    const float* Wsig = (const float*)d_in[8];
    const float* bsig = (const float*)d_in[9];
    const float* maxs = (const float*)d_in[10];
    const float* mins = (const float*)d_in[11];
    const float* maxr = (const float*)d_in[12];
    const float* minr = (const float*)d_in[13];
    float* out = (float*)d_out;
    unsigned short* ws = (unsigned short*)d_ws;

    int N = in_sizes[0] / (ENS * SDIM);        // 32768

    int prepBlocks = (WS_TOTAL + 255) / 256;
    prep_kernel<<<prepBlocks, 256, 0, stream>>>(W1, Wh, Wmu, Wsig, ws);

    int mainBlocks = (N / MT) * ENS;           // 3584
    ens_mlp_kernel<<<mainBlocks, 256, 0, stream>>>(s, a, b1, bh, bmu, bsig,
                                                   maxs, mins, maxr, minr, ws, out, N);
}

// Round 7
// 246.925 us; speedup vs baseline: 1.0719x; 1.0719x over previous
//
#include <hip/hip_runtime.h>
#include <hip/hip_bf16.h>

#define ENS 7
#define SDIM 30
#define ADIM 8
#define DIN 38          // SDIM + ADIM
#define HID 200
#define DOUT 31         // SDIM + RDIM
#define NHL 3           // hidden layers
#define HS 232          // hA row stride in elems (116 words -> 2-way max on b128 reads)
#define MT 64           // rows per block

typedef __bf16 bf16x8 __attribute__((ext_vector_type(8)));
typedef float f32x4 __attribute__((ext_vector_type(4)));

// ws layout (ushort elems): bf16 weights pre-swizzled into MFMA fragment order.
// Fragment (ct,st) = contiguous 512-ushort (1024 B) block at (ct*S + st)*512;
// element (lane, j) = W[k = st*32 + (lane>>4)*8 + j][n = ct*16 + (lane&15)]  (0 if OOB)
// Consumed as the MFMA A operand (m = out-col). Ownership (NT=13): wave w owns
// cts {3w,3w+1,3w+2} fully + row-slice rt=w of ct 12  -> perfect 13/13/13/13 balance.
#define U_L1 13312
#define U_H 46592
#define OFF_HD2 (U_L1 + NHL * U_H)            // 153088
#define PER_E (OFF_HD2 + 14336)               // 167424
#define WS_TOTAL (ENS * PER_E)                // 1171968 ushorts = 2.34 MB

__device__ __forceinline__ unsigned short f2bf(float f) {
    unsigned u = __float_as_uint(f);
    u += 0x7fffu + ((u >> 16) & 1u);          // RNE
    return (unsigned short)(u >> 16);
}

__device__ __forceinline__ unsigned pk2(float a, float b) {
    __hip_bfloat162 h = __float22bfloat162_rn(make_float2(a, b));
    return *reinterpret_cast<unsigned*>(&h);
}

__device__ __forceinline__ float softplusf(float x) {
    return fmaxf(x, 0.f) + __logf(1.f + __expf(-fabsf(x)));
}

// ---- prep: fp32 weights -> bf16 fragment-order in ws (layout unchanged since R4) ----
__global__ void prep_kernel(const float* __restrict__ W1, const float* __restrict__ Wh,
                            const float* __restrict__ Wmu, const float* __restrict__ Wsig,
                            unsigned short* __restrict__ ws) {
    int idx = blockIdx.x * 256 + threadIdx.x;
    if (idx >= WS_TOTAL) return;
    int e = idx / PER_E, r = idx % PER_E;
    int j = r & 7, lane = (r >> 3) & 63;
    int l16 = lane & 15, q = lane >> 4;
    float v = 0.f;
    if (r < U_L1) {                            // layer 1 (S=2)
        int fi = r >> 9;
        int ct = fi >> 1, st = fi & 1;
        int k = st * 32 + q * 8 + j, n = ct * 16 + l16;
        if (k < DIN && n < HID) v = W1[(e * DIN + k) * HID + n];
    } else if (r < OFF_HD2) {                  // hidden layers (S=7)
        int rh = r - U_L1;
        int l = rh / U_H, r2 = rh % U_H;
        int fi = r2 >> 9;
        int ct = fi / 7, st = fi % 7;
        int k = st * 32 + q * 8 + j, n = ct * 16 + l16;
        if (k < HID && n < HID) v = Wh[((l * ENS + e) * HID + (long)k) * HID + n];
    } else {                                   // heads (mu cols 0..30, sig cols 32..62)
        int r2 = r - OFF_HD2;
        int fi = r2 >> 9;
        int ct = fi / 7, st = fi % 7;
        int k = st * 32 + q * 8 + j, n = ct * 16 + l16;
        if (k < HID) {
            if (n < DOUT) v = Wmu[(e * HID + k) * DOUT + n];
            else if (n >= 32 && n < 32 + DOUT) v = Wsig[(e * HID + k) * DOUT + (n - 32)];
        }
    }
    ws[idx] = f2bf(v);
}

// One layer, balanced ownership. Weights = A operand, activations (LDS) = B operand.
// D[m = out-col][n = batch-row]: lane holds 4 consecutive out-cols of row (l16-based).
// At the last K-step, prefetches the NEXT layer's st=0 fragments into bq (these have
// no hA dependency, so they issue before the epilogue barrier and hide L2 latency).
template<int S, int OWN, bool SH, int NS, int NOWN, bool NSH>
__device__ __forceinline__ void runLayer(const unsigned short* __restrict__ fo,
                                         const unsigned short* __restrict__ fs,
                                         const unsigned short* __restrict__ nfo,
                                         const unsigned short* __restrict__ nfs,
                                         const unsigned short* hA,
                                         int swv, int l16, int quad,
                                         f32x4 (&accO)[4][3], f32x4& accS,
                                         bf16x8 (&bq)[4]) {
#pragma unroll
    for (int r = 0; r < 4; r++)
#pragma unroll
        for (int c = 0; c < 3; c++) accO[r][c] = (f32x4){0.f, 0.f, 0.f, 0.f};
    accS = (f32x4){0.f, 0.f, 0.f, 0.f};

#pragma unroll
    for (int st = 0; st < S; ++st) {
        bf16x8 bn[4];
        if (st + 1 < S) {
#pragma unroll
            for (int c = 0; c < OWN; c++) bn[c] = *((const bf16x8*)(fo + (c * S + st + 1) * 512));
            if (SH) bn[3] = *((const bf16x8*)(fs + (st + 1) * 512));
        } else if (NS > 0) {
#pragma unroll
            for (int c = 0; c < NOWN; c++) bn[c] = *((const bf16x8*)(nfo + (c * NS) * 512));
            if (NSH) bn[3] = *((const bf16x8*)(nfs));
        }
        bf16x8 af[4];
#pragma unroll
        for (int r = 0; r < 4; r++)
            af[r] = *((const bf16x8*)(hA + (r * 16 + l16) * HS + st * 32 + quad * 8));
        bf16x8 afs;
        if (SH) afs = *((const bf16x8*)(hA + (swv * 16 + l16) * HS + st * 32 + quad * 8));
#pragma unroll
        for (int c = 0; c < OWN; c++)
#pragma unroll
            for (int r = 0; r < 4; r++)
                accO[r][c] = __builtin_amdgcn_mfma_f32_16x16x32_bf16(bq[c], af[r], accO[r][c], 0, 0, 0);
        if (SH) accS = __builtin_amdgcn_mfma_f32_16x16x32_bf16(bq[3], afs, accS, 0, 0, 0);
        if (st + 1 < S || NS > 0) {
#pragma unroll
            for (int c = 0; c < 4; c++) bq[c] = bn[c];
        }
    }
}

// ---- fused 5-layer ensemble MLP ----
// R6 post-mortem: (256,4) capped regs at 128/wave -> accumulator spill
// (WRITE_SIZE 77->125 MB, VGPR_Count 64). (256,3) gives ~170/wave: fits.
__launch_bounds__(256, 3)
__global__ void ens_mlp_kernel(const float* __restrict__ s, const float* __restrict__ a,
                               const float* __restrict__ b1, const float* __restrict__ bh,
                               const float* __restrict__ bmu, const float* __restrict__ bsig,
                               const float* __restrict__ maxs, const float* __restrict__ mins,
                               const float* __restrict__ maxr, const float* __restrict__ minr,
                               const unsigned short* __restrict__ ws,
                               float* __restrict__ out, int N) {
    __shared__ unsigned short hA[MT * HS];     // 29696 B, activations (bf16) -- only LDS

    const int tid = threadIdx.x;
    const int wv = tid >> 6, lane = tid & 63;
    const int quad = lane >> 4, l16 = lane & 15;
    const int swv = __builtin_amdgcn_readfirstlane(wv);   // wave-uniform -> SGPR addressing
    const int bid = blockIdx.x;
    const int e = bid % ENS, n0 = (bid / ENS) * MT;

    // zero hA (K-pad cols must be 0)
    for (int i = tid; i < MT * HS / 8; i += 256) ((uint4*)hA)[i] = make_uint4(0, 0, 0, 0);
    __syncthreads();

    // stage x = concat(s, a) -> hA cols 0..37 (bf16)
    {
        int m = tid & 63, cg = tid >> 6;
        long g = n0 + m;
        const float* srow = s + (g * ENS + e) * SDIM;
        const float* arow = a + (g * ENS + e) * ADIM;
#pragma unroll
        for (int k = 0; k < 10; k++) {
            int c = cg * 10 + k;
            if (c < DIN) {
                float v = (c < SDIM) ? srow[c] : arow[c - SDIM];
                hA[m * HS + c] = f2bf(v);
            }
        }
    }
    __syncthreads();

    // scalar fragment base pointers (+ lane*16 B per-lane part)
    const unsigned short* we = ws + e * PER_E;
    const unsigned short* L1o = we + swv * 3 * 2 * 512 + lane * 8;
    const unsigned short* L1s = we + 12 * 2 * 512 + lane * 8;
    const unsigned short* H0o = we + U_L1 + swv * 3 * 7 * 512 + lane * 8;
    const unsigned short* H0s = we + U_L1 + 12 * 7 * 512 + lane * 8;
    const unsigned short* H1o = H0o + U_H;
    const unsigned short* H1s = H0s + U_H;
    const unsigned short* H2o = H1o + U_H;
    const unsigned short* H2s = H1s + U_H;
    const unsigned short* HDo = we + OFF_HD2 + swv * 7 * 512 + lane * 8;

    f32x4 accO[4][3];   // own col-tiles: [row-tile][c]
    f32x4 accS;         // shared ct12, row-tile = swv
    bf16x8 bq[4];

    // bias + swish -> hA. Own cts: col < 192 always (unconditional float4 bias).
    // Shared ct12: cols 192..207; pad cols (>=200) have zero weights+bias -> writes 0,
    // which is exactly the K-pad zero the next layer needs.
    auto epiH = [&](const float* bias) {
#pragma unroll
        for (int c = 0; c < 3; c++) {
            int col = (3 * swv + c) * 16 + quad * 4;
            float4 bc4 = *((const float4*)(bias + col));
#pragma unroll
            for (int r = 0; r < 4; r++) {
                float v0 = accO[r][c][0] + bc4.x, v1 = accO[r][c][1] + bc4.y;
                float v2 = accO[r][c][2] + bc4.z, v3 = accO[r][c][3] + bc4.w;
                v0 *= __builtin_amdgcn_rcpf(1.f + __expf(-v0));
                v1 *= __builtin_amdgcn_rcpf(1.f + __expf(-v1));
                v2 *= __builtin_amdgcn_rcpf(1.f + __expf(-v2));
                v3 *= __builtin_amdgcn_rcpf(1.f + __expf(-v3));
                *((uint2*)(hA + (r * 16 + l16) * HS + col)) = make_uint2(pk2(v0, v1), pk2(v2, v3));
            }
        }
        {
            int col = 192 + quad * 4;
            float4 bc4 = make_float4(0.f, 0.f, 0.f, 0.f);
            if (col < HID) bc4 = *((const float4*)(bias + col));   // quad 0,1 only
            float v0 = accS[0] + bc4.x, v1 = accS[1] + bc4.y;
            float v2 = accS[2] + bc4.z, v3 = accS[3] + bc4.w;
            v0 *= __builtin_amdgcn_rcpf(1.f + __expf(-v0));
            v1 *= __builtin_amdgcn_rcpf(1.f + __expf(-v1));
            v2 *= __builtin_amdgcn_rcpf(1.f + __expf(-v2));
            v3 *= __builtin_amdgcn_rcpf(1.f + __expf(-v3));
            *((uint2*)(hA + (swv * 16 + l16) * HS + col)) = make_uint2(pk2(v0, v1), pk2(v2, v3));
        }
    };

    // initial fragment load (L1, st=0)
#pragma unroll
    for (int c = 0; c < 3; c++) bq[c] = *((const bf16x8*)(L1o + (c * 2) * 512));
    bq[3] = *((const bf16x8*)(L1s));

    runLayer<2, 3, true, 7, 3, true>(L1o, L1s, H0o, H0s, hA, swv, l16, quad, accO, accS, bq);
    __syncthreads();
    epiH(b1 + e * HID);
    __syncthreads();
    runLayer<7, 3, true, 7, 3, true>(H0o, H0s, H1o, H1s, hA, swv, l16, quad, accO, accS, bq);
    __syncthreads();
    epiH(bh + (0 * ENS + e) * HID);
    __syncthreads();
    runLayer<7, 3, true, 7, 3, true>(H1o, H1s, H2o, H2s, hA, swv, l16, quad, accO, accS, bq);
    __syncthreads();
    epiH(bh + (1 * ENS + e) * HID);
    __syncthreads();
    runLayer<7, 3, true, 7, 1, false>(H2o, H2s, HDo, (const unsigned short*)nullptr,
                                      hA, swv, l16, quad, accO, accS, bq);
    __syncthreads();
    epiH(bh + (2 * ENS + e) * HID);
    __syncthreads();
    runLayer<7, 1, false, 0, 0, false>(HDo, (const unsigned short*)nullptr,
                                       (const unsigned short*)nullptr, (const unsigned short*)nullptr,
                                       hA, swv, l16, quad, accO, accS, bq);
    // no barrier: head tail reads only registers, writes only global

    // head tail: wave owns ct = swv -> lane holds cols swv*16+quad*4+{0..3}
    // (mu block 0..31 for swv<2, sigma block 32..63 for swv>=2), rows r*16+l16.
    const long off1 = (long)N * ENS * SDIM;    // ds_sg
    const long off2 = 2 * off1;                // r_mu
    const long off3 = off2 + (long)N * ENS;    // r_sg
    {
        const bool isSig = (swv >= 2);
        const int c0 = (swv & 1) * 16 + quad * 4;
        float bias_i[4], mx_i[4], mn_i[4];
#pragma unroll
        for (int i = 0; i < 4; i++) {
            int c = c0 + i;
            bias_i[i] = (c < DOUT) ? (isSig ? bsig : bmu)[e * DOUT + c] : 0.f;
            if (isSig) {
                mx_i[i] = (c < SDIM) ? maxs[c] : maxr[0];
                mn_i[i] = (c < SDIM) ? mins[c] : minr[0];
            }
        }
#pragma unroll
        for (int r = 0; r < 4; r++) {
            long g = n0 + r * 16 + l16;
            long rowbase = (g * ENS + e) * SDIM;
#pragma unroll
            for (int i = 0; i < 4; i++) {
                int c = c0 + i;
                if (c < DOUT) {
                    float v = accO[r][0][i] + bias_i[i];
                    if (!isSig) {
                        if (c < SDIM) out[rowbase + c] = v;
                        else out[off2 + g * ENS + e] = v;
                    } else {
                        v = 0.5f * (mx_i[i] - softplusf(mx_i[i] - 2.f * v));
                        v = 0.5f * (mn_i[i] + softplusf(2.f * v - mn_i[i]));
                        v = __expf(v);
                        if (c < SDIM) out[off1 + rowbase + c] = v;
                        else out[off3 + g * ENS + e] = v;
                    }
                }
            }
        }
    }
}

extern "C" void kernel_launch(void* const* d_in, const int* in_sizes, int n_in,
                              void* d_out, int out_size, void* d_ws, size_t ws_size,
                              hipStream_t stream) {
    const float* s    = (const float*)d_in[0];
    const float* a    = (const float*)d_in[1];
    const float* W1   = (const float*)d_in[2];
    const float* b1   = (const float*)d_in[3];
    const float* Wh   = (const float*)d_in[4];
    const float* bh   = (const float*)d_in[5];
    const float* Wmu  = (const float*)d_in[6];
    const float* bmu  = (const float*)d_in[7];
    const float* Wsig = (const float*)d_in[8];
    const float* bsig = (const float*)d_in[9];
    const float* maxs = (const float*)d_in[10];
    const float* mins = (const float*)d_in[11];
    const float* maxr = (const float*)d_in[12];
    const float* minr = (const float*)d_in[13];
    float* out = (float*)d_out;
    unsigned short* ws = (unsigned short*)d_ws;

    int N = in_sizes[0] / (ENS * SDIM);        // 32768

    int prepBlocks = (WS_TOTAL + 255) / 256;
    prep_kernel<<<prepBlocks, 256, 0, stream>>>(W1, Wh, Wmu, Wsig, ws);

    int mainBlocks = (N / MT) * ENS;           // 3584
    ens_mlp_kernel<<<mainBlocks, 256, 0, stream>>>(s, a, b1, bh, bmu, bsig,
                                                   maxs, mins, maxr, minr, ws, out, N);
}